// Round 3
// baseline (362.412 us; speedup 1.0000x reference)
//
#include <hip/hip_runtime.h>

// De-emphasis IIR: y[n] = x[n] + C*y[n-1] per row, 64 rows of 480000 fp32.
// Affine-map scan: per-thread serial scan of 32 elems (registers), wave-level
// shfl affine scan, tiny LDS scan across the 4 waves of a 256-thread block.
// Cross-block carry approximated by a 512-element halo: 0.97^512 ~ 1.7e-7,
// truncation error ~3e-6 << fp32 association noise (~0.06).
//
// R2 rationale: R1 (1024-thr blocks, 16-wave barriers, 2 blocks/CU) was
// convoy/latency-bound at 2.34 TB/s, 10% VALU. Smaller sync domains (4-wave
// barriers, 8 blocks/CU) + deeper per-thread work target latency hiding.
// R3: fix nontemporal builtin — needs clang ext_vector_type, not HIP float4.

#define COEFF 0.97f
#define ROW_LEN 480000
#define SEG 32                          // elements per thread
#define BLOCK 256                       // threads per block (4 waves)
#define HALO 512                        // halo elements (16 threads' worth)
#define HALO_THREADS (HALO / SEG)       // 16
#define SPAN (BLOCK * SEG)              // 8192 elements scanned per block
#define OUT_PER_BLOCK (SPAN - HALO)     // 7680 elements written per block
#define BLOCKS_PER_ROW ((ROW_LEN + OUT_PER_BLOCK - 1) / OUT_PER_BLOCK)  // 63

typedef float v4f __attribute__((ext_vector_type(4)));

constexpr float fpow(float b, int n) {
    float r = 1.0f;
    for (int i = 0; i < n; ++i) r *= b;
    return r;
}
constexpr float CSEG      = fpow(COEFF, SEG);         // per-segment decay 0.97^32
constexpr float CWAVESPAN = fpow(COEFF, 64 * SEG);    // per-wave decay 0.97^2048 (~8e-28)

struct Pows { float p[SEG + 1]; };
constexpr Pows make_pows() {
    Pows P{};
    float r = 1.0f;
    for (int i = 0; i <= SEG; ++i) { P.p[i] = r; r *= COEFF; }
    return P;
}
constexpr Pows PW = make_pows();   // PW.p[i] = COEFF^i

__global__ __launch_bounds__(BLOCK) void deemph_kernel(const float* __restrict__ x,
                                                       float* __restrict__ y) {
    const int row  = blockIdx.y;
    const int blk  = blockIdx.x;
    const int t    = threadIdx.x;
    const int lane = t & 63;
    const int wave = t >> 6;

    const long long row_base = (long long)row * ROW_LEN;
    const int out_start = blk * OUT_PER_BLOCK;
    const int seg_start = out_start - HALO + t * SEG;  // multiple of 32; may be <0 or >=ROW_LEN

    // ---- load 32 elements (zero-fill outside row: exact at row start,
    //      don't-care past row end) ----
    float l[SEG];
    const bool in_row = (seg_start >= 0) && (seg_start < ROW_LEN);
    if (in_row) {
        const v4f* p = (const v4f*)(x + row_base + seg_start);
        #pragma unroll
        for (int q = 0; q < SEG / 4; ++q) {
            v4f v = p[q];
            l[4*q+0] = v.x; l[4*q+1] = v.y; l[4*q+2] = v.z; l[4*q+3] = v.w;
        }
    } else {
        #pragma unroll
        for (int i = 0; i < SEG; ++i) l[i] = 0.0f;
    }

    // ---- local inclusive scan with zero carry-in (serial, unavoidable) ----
    #pragma unroll
    for (int i = 1; i < SEG; ++i) l[i] = fmaf(COEFF, l[i-1], l[i]);

    // ---- wave-level inclusive affine scan over segment maps (A,B):
    //      combine(left,right) = (A_l*A_r, A_r*B_l + B_r) ----
    float A = CSEG;
    float B = l[SEG-1];
    #pragma unroll
    for (int d = 1; d < 64; d <<= 1) {
        float Ap = __shfl_up(A, d);
        float Bp = __shfl_up(B, d);
        if (lane >= d) { B = fmaf(A, Bp, B); A *= Ap; }
    }
    // exclusive carry into this thread from earlier threads in the wave
    float Aex = __shfl_up(A, 1);
    float Bex = __shfl_up(B, 1);
    if (lane == 0) { Aex = 1.0f; Bex = 0.0f; }

    // ---- cross-wave: scan the 4 wave totals via LDS ----
    __shared__ float wsum[BLOCK / 64];
    if (lane == 63) wsum[wave] = B;   // inclusive wave total
    __syncthreads();
    float Cw = 0.0f;                  // carry into this wave
    #pragma unroll
    for (int v = 0; v < BLOCK / 64 - 1; ++v)
        if (v < wave) Cw = fmaf(CWAVESPAN, Cw, wsum[v]);

    // total carry into this thread's segment
    const float K = fmaf(Aex, Cw, Bex);

    // ---- apply carry with precomputed powers (independent FMAs) ----
    #pragma unroll
    for (int i = 0; i < SEG; ++i) l[i] = fmaf(K, PW.p[i + 1], l[i]);

    // ---- store (only non-halo, in-row segments); nontemporal to spare L3 ----
    if (t >= HALO_THREADS && seg_start < ROW_LEN) {
        v4f* q = (v4f*)(y + row_base + seg_start);
        #pragma unroll
        for (int j = 0; j < SEG / 4; ++j) {
            v4f v;
            v.x = l[4*j+0]; v.y = l[4*j+1]; v.z = l[4*j+2]; v.w = l[4*j+3];
            __builtin_nontemporal_store(v, q + j);
        }
    }
}

extern "C" void kernel_launch(void* const* d_in, const int* in_sizes, int n_in,
                              void* d_out, int out_size, void* d_ws, size_t ws_size,
                              hipStream_t stream) {
    (void)n_in; (void)d_ws; (void)ws_size; (void)out_size;
    const float* x = (const float*)d_in[0];
    float* y = (float*)d_out;
    const int n_rows = in_sizes[0] / ROW_LEN;  // 64 for (32,2,480000)
    dim3 grid(BLOCKS_PER_ROW, n_rows);
    deemph_kernel<<<grid, BLOCK, 0, stream>>>(x, y);
}

// Round 4
// 215.905 us; speedup vs baseline: 1.6786x; 1.6786x over previous
//
#include <hip/hip_runtime.h>

// De-emphasis IIR: y[n] = x[n] + C*y[n-1] per row, 64 rows of 480000 fp32.
//
// R4 structure (post-mortem of R1-R3): the per-thread-contiguous layout made
// every global access address-divergent (64 lines per wave instr) — R1 hit
// only 2.34 TB/s, and nontemporal stores (R3) turned that into 3.5x HBM write
// amplification. Fix: coalesced global <-> LDS transpose (CUB-style).
//   A: coalesced float4 loads -> LDS (XOR-swizzled chunks, conflict-free)
//   B: thread reads its contiguous 16-elem segment from LDS, scans in regs,
//      wave shfl affine scan + 4-wave LDS combine (verified R1/R2 core)
//   C: results back to LDS (own chunks, no barrier needed before this)
//   D: coalesced float4 stores
// Cross-block carry: 512-elem halo; 0.97^512 ~ 1.7e-7 (validated: absmax
// 0.0625 = fp32 association noise, threshold 0.4475).

#define COEFF 0.97f
#define ROW_LEN 480000
#define SEG 16                           // elements per thread
#define BLOCK 256                        // threads per block (4 waves)
#define HALO 512                         // halo elements
#define SPAN (BLOCK * SEG)               // 4096 elements per block span
#define OUT_PER_BLOCK (SPAN - HALO)      // 3584 elements written per block
#define BLOCKS_PER_ROW ((ROW_LEN + OUT_PER_BLOCK - 1) / OUT_PER_BLOCK)  // 134
#define CHUNKS (SPAN / 4)                // 1024 float4 chunks in LDS
#define HALO_CHUNKS (HALO / 4)           // 128
#define CPT (SEG / 4)                    // 4 chunks per thread
#define K_ITERS (CHUNKS / BLOCK)         // 4 coalesced chunks per thread

typedef float v4f __attribute__((ext_vector_type(4)));

constexpr float fpow(float b, int n) {
    float r = 1.0f;
    for (int i = 0; i < n; ++i) r *= b;
    return r;
}
constexpr float CSEG      = fpow(COEFF, SEG);        // 0.97^16
constexpr float CWAVESPAN = fpow(COEFF, 64 * SEG);   // 0.97^1024 ~ 2.8e-14

struct Pows { float p[SEG + 1]; };
constexpr Pows make_pows() {
    Pows P{};
    float r = 1.0f;
    for (int i = 0; i <= SEG; ++i) { P.p[i] = r; r *= COEFF; }
    return P;
}
constexpr Pows PW = make_pows();   // PW.p[i] = COEFF^i

// XOR swizzle on chunk index: owner o = m>>2 holds chunks with local idx
// c = m&3 at physical (o<<2) | (c ^ ((o>>1)&3)). Spreads both the
// per-thread-segment access (B/C) and the coalesced access (A/D) across all
// 8 bank-quads -> minimum LDS cycles, zero conflicts.
__device__ __forceinline__ int swz(int m) {
    const int o = m >> 2, c = m & 3;
    return (o << 2) | (c ^ ((o >> 1) & 3));
}

__global__ __launch_bounds__(BLOCK) void deemph_kernel(const float* __restrict__ x,
                                                       float* __restrict__ y) {
    __shared__ v4f lds[CHUNKS];            // 16 KiB
    __shared__ float wsum[BLOCK / 64];

    const int row  = blockIdx.y;
    const int blk  = blockIdx.x;
    const int t    = threadIdx.x;
    const int lane = t & 63;
    const int wave = t >> 6;

    const long long row_base = (long long)row * ROW_LEN;
    const int span_start = blk * OUT_PER_BLOCK - HALO;  // may be <0 (blk 0)

    // ---- Phase A: coalesced global loads -> swizzled LDS ----
    #pragma unroll
    for (int k = 0; k < K_ITERS; ++k) {
        const int m = t + k * BLOCK;          // logical chunk index
        const int e = span_start + 4 * m;     // element index in row
        v4f v = {0.0f, 0.0f, 0.0f, 0.0f};     // zero-fill outside row
        if (e >= 0 && e < ROW_LEN)
            v = *(const v4f*)(x + row_base + e);
        lds[swz(m)] = v;
    }
    __syncthreads();

    // ---- Phase B: read own contiguous segment from LDS ----
    float l[SEG];
    #pragma unroll
    for (int c = 0; c < CPT; ++c) {
        v4f v = lds[swz(t * CPT + c)];
        l[4*c+0] = v.x; l[4*c+1] = v.y; l[4*c+2] = v.z; l[4*c+3] = v.w;
    }

    // ---- local inclusive scan (zero carry-in) ----
    #pragma unroll
    for (int i = 1; i < SEG; ++i) l[i] = fmaf(COEFF, l[i-1], l[i]);

    // ---- wave-level inclusive affine scan over segment maps (A,B):
    //      combine(left,right) = (A_l*A_r, A_r*B_l + B_r) ----
    float A = CSEG;
    float B = l[SEG-1];
    #pragma unroll
    for (int d = 1; d < 64; d <<= 1) {
        float Ap = __shfl_up(A, d);
        float Bp = __shfl_up(B, d);
        if (lane >= d) { B = fmaf(A, Bp, B); A *= Ap; }
    }
    // exclusive carry into this thread from earlier threads in the wave
    float Aex = __shfl_up(A, 1);
    float Bex = __shfl_up(B, 1);
    if (lane == 0) { Aex = 1.0f; Bex = 0.0f; }

    // ---- cross-wave combine (4 waves) ----
    if (lane == 63) wsum[wave] = B;
    __syncthreads();
    float Cw = 0.0f;
    #pragma unroll
    for (int v = 0; v < BLOCK / 64 - 1; ++v)
        if (v < wave) Cw = fmaf(CWAVESPAN, Cw, wsum[v]);

    const float K = fmaf(Aex, Cw, Bex);   // carry into this thread's segment

    // ---- apply carry with precomputed powers ----
    #pragma unroll
    for (int i = 0; i < SEG; ++i) l[i] = fmaf(K, PW.p[i + 1], l[i]);

    // ---- Phase C: write own segment back (own chunks only; the phase-A
    //      barrier already separated these slots from other threads) ----
    #pragma unroll
    for (int c = 0; c < CPT; ++c) {
        v4f v;
        v.x = l[4*c+0]; v.y = l[4*c+1]; v.z = l[4*c+2]; v.w = l[4*c+3];
        lds[swz(t * CPT + c)] = v;
    }
    __syncthreads();

    // ---- Phase D: coalesced global stores (skip halo, clamp row end) ----
    #pragma unroll
    for (int k = 0; k < K_ITERS; ++k) {
        const int m = t + k * BLOCK;
        const int e = span_start + 4 * m;
        if (m >= HALO_CHUNKS && e < ROW_LEN)
            *(v4f*)(y + row_base + e) = lds[swz(m)];
    }
}

extern "C" void kernel_launch(void* const* d_in, const int* in_sizes, int n_in,
                              void* d_out, int out_size, void* d_ws, size_t ws_size,
                              hipStream_t stream) {
    (void)n_in; (void)d_ws; (void)ws_size; (void)out_size;
    const float* x = (const float*)d_in[0];
    float* y = (float*)d_out;
    const int n_rows = in_sizes[0] / ROW_LEN;  // 64 for (32,2,480000)
    dim3 grid(BLOCKS_PER_ROW, n_rows);
    deemph_kernel<<<grid, BLOCK, 0, stream>>>(x, y);
}